// Round 3
// baseline (234.912 us; speedup 1.0000x reference)
//
#include <hip/hip_runtime.h>

// Problem constants: B=4, C=256, HS=WS=64 -> N=4096 pixels/batch, 16384 total.
// NK=NV=32, NH=8, QKV = 32*32+32+32 = 1088, NH*QKV = 8704.
#define NPIX_TOTAL 16384
#define CDIM 256
#define NHEADS 8
#define QKVD 1088
#define NQKV 8704

typedef unsigned short u16;
typedef __attribute__((ext_vector_type(8))) __bf16 bf16x8;
typedef __attribute__((ext_vector_type(4))) float f32x4;
typedef __attribute__((ext_vector_type(2))) unsigned u32x2;

__device__ static inline u16 f2bf(float f) {
  union { float f; unsigned u; } x; x.f = f;
  unsigned r = x.u + 0x7fffu + ((x.u >> 16) & 1u);   // round-to-nearest-even
  return (u16)(r >> 16);
}
__device__ static inline float bf2f(u16 b) {
  union { unsigned u; float f; } x; x.u = ((unsigned)b) << 16;
  return x.f;
}

// async global->LDS, 16B per lane; LDS dest is wave-uniform base + lane*16 (HW)
__device__ static inline void gload_lds16(const void* g, void* l) {
  __builtin_amdgcn_global_load_lds((const __attribute__((address_space(1))) void*)g,
                                   (__attribute__((address_space(3))) void*)l,
                                   16, 0, 0);
}

#define WAITVM(N) asm volatile("s_waitcnt vmcnt(" #N ")" ::: "memory")

// ---------------------------------------------------------------------------
// x (B, C, 4096) f32  ->  Xbf (B*4096, 256) bf16   (transpose via LDS tile)
__global__ __launch_bounds__(256) void transpose_cast(const float* __restrict__ x,
                                                      u16* __restrict__ xt) {
  __shared__ float t[64][65];
  const int b = blockIdx.z;
  const float* xb = x + (size_t)b * CDIM * 4096;
  u16* ob = xt + (size_t)b * 4096 * CDIM;
  const int n0 = blockIdx.x * 64;
  const int c0 = blockIdx.y * 64;
  const int tx = threadIdx.x & 63;
  const int ty = threadIdx.x >> 6;
#pragma unroll
  for (int i = 0; i < 16; ++i)
    t[ty + i * 4][tx] = xb[(size_t)(c0 + ty + i * 4) * 4096 + n0 + tx];
  __syncthreads();
#pragma unroll
  for (int i = 0; i < 16; ++i)
    ob[(size_t)(n0 + ty + i * 4) * CDIM + c0 + tx] = f2bf(t[tx][ty + i * 4]);
}

// f32 -> bf16 elementwise (n divisible by 1024 per launch config)
__global__ __launch_bounds__(256) void cast_bf(const float* __restrict__ in,
                                               u16* __restrict__ out, int n) {
  const int i = (blockIdx.x * 256 + threadIdx.x) * 4;
  if (i >= n) return;
  const f32x4 v = *(const f32x4*)(in + i);
  u16 o0 = f2bf(v.x), o1 = f2bf(v.y), o2 = f2bf(v.z), o3 = f2bf(v.w);
  *(unsigned*)(out + i) = (unsigned)o0 | ((unsigned)o1 << 16);
  *(unsigned*)(out + i + 2) = (unsigned)o2 | ((unsigned)o3 << 16);
}

// ---------------------------------------------------------------------------
// gemm1: qkv = Xbf @ Wbf^T (NT, K=256). 256x256 tile, BK=64, 512 thr = 8 waves
// (2 M-halves x 4 N-quarters), per-wave 128x64 output (8x4 fragments).
// Counted-vmcnt schedule (T3+T4): raw s_barrier + s_waitcnt vmcnt(8), loads
// stay in flight across barriers; double-buffered 64KB K-slabs (128KB LDS).
// XOR chunk swizzle (T2): global source pre-swizzled, LDS linear, read XORed.
// Swapped-operand MFMA -> D transposed -> packed 8B bf16 stores.
__global__ __launch_bounds__(512, 2) void gemm1_qkv(const u16* __restrict__ A,
                                                    const u16* __restrict__ B,
                                                    u16* __restrict__ C,
                                                    int ntile_n) {
  __shared__ u16 lds[2][2][16384];  // [buf][mat][32KB slab] = 128 KB
  const int tid = threadIdx.x;
  const int lane = tid & 63;
  const int wid = tid >> 6;   // 0..7
  const int wr = wid >> 2;    // 0..1  M half
  const int wc = wid & 3;     // 0..3  N quarter
  // XCD-chunked bijective swizzle (gridDim.x % 8 == 0)
  const int cpx = gridDim.x >> 3;
  const int bid = (blockIdx.x & 7) * cpx + (blockIdx.x >> 3);
  const size_t m0 = (size_t)(bid / ntile_n) * 256;
  const size_t n0 = (size_t)(bid % ntile_n) * 256;
  const int frow = lane & 15;
  const int fh = lane >> 4;
  const int fsw = frow & 7;

  f32x4 acc[8][4] = {};

  // stage one K-step (kt) of A and B into buf: 8 gloads/wave (A0,B0,...,A3,B3)
  auto stage = [&](int buf, int kt) {
#pragma unroll
    for (int i = 0; i < 4; ++i) {
      const int L = (wid * 4 + i) * 64 + lane;  // 16B-chunk id 0..2047
      const int r = L >> 3;                     // slab row 0..255
      const int c = (L & 7) ^ (r & 7);          // swizzled source chunk
      const size_t go = (size_t)r * CDIM + kt * 64 + c * 8;
      gload_lds16(A + m0 * CDIM + go, (char*)&lds[buf][0][0] + (size_t)(wid * 4 + i) * 1024);
      gload_lds16(B + n0 * CDIM + go, (char*)&lds[buf][1][0] + (size_t)(wid * 4 + i) * 1024);
    }
  };

  auto compute = [&](int buf) {
    const u16* as = &lds[buf][0][0];
    const u16* bs = &lds[buf][1][0];
#pragma unroll
    for (int kk2 = 0; kk2 < 2; ++kk2) {
      const int kc = ((kk2 * 4 + fh) ^ fsw) * 8;
      bf16x8 bfr[4];
#pragma unroll
      for (int ni = 0; ni < 4; ++ni)
        bfr[ni] = *(const bf16x8*)(bs + (wc * 64 + ni * 16 + frow) * 64 + kc);
#pragma unroll
      for (int mh = 0; mh < 2; ++mh) {
        bf16x8 af[4];
#pragma unroll
        for (int mi = 0; mi < 4; ++mi)
          af[mi] = *(const bf16x8*)(as + (wr * 128 + (mh * 4 + mi) * 16 + frow) * 64 + kc);
        __builtin_amdgcn_s_setprio(1);
#pragma unroll
        for (int mi = 0; mi < 4; ++mi)
#pragma unroll
          for (int ni = 0; ni < 4; ++ni)
            acc[mh * 4 + mi][ni] = __builtin_amdgcn_mfma_f32_16x16x32_bf16(
                bfr[ni], af[mi], acc[mh * 4 + mi][ni], 0, 0, 0);
        __builtin_amdgcn_s_setprio(0);
      }
    }
  };

  stage(0, 0);
  stage(1, 1);
  WAITVM(8);                          // kt0 landed (mine); barrier -> everyone's
  __builtin_amdgcn_s_barrier();
  compute(0);                         // kt0
  __builtin_amdgcn_s_barrier();       // all reads of buf0 done
  stage(0, 2);
  WAITVM(8);                          // kt1 landed (kt2 still in flight)
  __builtin_amdgcn_s_barrier();
  compute(1);                         // kt1
  __builtin_amdgcn_s_barrier();
  stage(1, 3);
  WAITVM(8);                          // kt2 landed (kt3 still in flight)
  __builtin_amdgcn_s_barrier();
  compute(0);                         // kt2
  WAITVM(0);                          // kt3 landed
  __builtin_amdgcn_s_barrier();
  compute(1);                         // kt3

  // D transposed (swapped operands): col(lane&15)=pixel, row((lane>>4)*4+j)=n
#pragma unroll
  for (int mf = 0; mf < 8; ++mf)
#pragma unroll
    for (int ni = 0; ni < 4; ++ni) {
      const size_t gm = m0 + wr * 128 + mf * 16 + frow;
      const size_t gn = n0 + wc * 64 + ni * 16 + fh * 4;
      const f32x4 v = acc[mf][ni];
      u32x2 p;
      p.x = (unsigned)f2bf(v.x) | ((unsigned)f2bf(v.y) << 16);
      p.y = (unsigned)f2bf(v.z) | ((unsigned)f2bf(v.w) << 16);
      *(u32x2*)(C + gm * (size_t)NQKV + gn) = p;
    }
}

// ---------------------------------------------------------------------------
// gemm2 (old 128x128 2-phase structure, adequate: write-bound ~64MB f32 out).
// out = a @ Wc^T + bc, written transposed to (B, C, 4096).
__global__ __launch_bounds__(256, 2) void gemm_out(const u16* __restrict__ A,
                                                   const u16* __restrict__ B,
                                                   float* __restrict__ Cout,
                                                   const float* __restrict__ bias) {
  __shared__ u16 As[2][128 * 64];
  __shared__ u16 Bs[2][128 * 64];
  const int tid = threadIdx.x;
  const int lane = tid & 63;
  const int wv = tid >> 6;
  const size_t m0 = (size_t)blockIdx.y * 128;
  const size_t n0 = (size_t)blockIdx.x * 128;
  const int wm = (wv >> 1) * 64;
  const int wn = (wv & 1) * 64;
  const int frow = lane & 15;
  const int fh = lane >> 4;
  const int fsw = frow & 7;

  f32x4 acc[4][4] = {};

  auto stage = [&](int buf, int kt) {
#pragma unroll
    for (int i = 0; i < 4; ++i) {
      const int L = (i * 4 + wv) * 64 + lane;
      const int r = L >> 3;
      const int cs = (L & 7) ^ (r & 7);
      const size_t goff = (size_t)r * CDIM + kt * 64 + cs * 8;
      gload_lds16(A + m0 * CDIM + goff, (char*)As[buf] + (size_t)(i * 4 + wv) * 1024);
      gload_lds16(B + n0 * CDIM + goff, (char*)Bs[buf] + (size_t)(i * 4 + wv) * 1024);
    }
  };

  stage(0, 0);
#pragma unroll
  for (int kt = 0; kt < 4; ++kt) {
    __syncthreads();
    if (kt < 3) stage((kt + 1) & 1, kt + 1);
    const u16* as = As[kt & 1];
    const u16* bs = Bs[kt & 1];
#pragma unroll
    for (int kk2 = 0; kk2 < 2; ++kk2) {
      const int kc = (kk2 * 4 + fh) ^ fsw;
      bf16x8 af[4], bfr[4];
#pragma unroll
      for (int mi = 0; mi < 4; ++mi)
        af[mi] = *(const bf16x8*)(as + (wm + mi * 16 + frow) * 64 + kc * 8);
#pragma unroll
      for (int ni = 0; ni < 4; ++ni)
        bfr[ni] = *(const bf16x8*)(bs + (wn + ni * 16 + frow) * 64 + kc * 8);
#pragma unroll
      for (int mi = 0; mi < 4; ++mi)
#pragma unroll
        for (int ni = 0; ni < 4; ++ni)
          acc[mi][ni] =
              __builtin_amdgcn_mfma_f32_16x16x32_bf16(af[mi], bfr[ni], acc[mi][ni], 0, 0, 0);
    }
  }

  // normal D: col(lane&15)=n, row((lane>>4)*4+j)=pixel
#pragma unroll
  for (int mi = 0; mi < 4; ++mi)
#pragma unroll
    for (int ni = 0; ni < 4; ++ni) {
      const size_t gm = m0 + wm + mi * 16 + fh * 4;
      const size_t gn = n0 + wn + ni * 16 + frow;
      f32x4 v = acc[mi][ni];
      v += bias[gn];
      const size_t b = gm >> 12;
      const size_t pix = gm & 4095;
      *(f32x4*)(Cout + ((b << 8) + gn) * 4096 + pix) = v;
    }
}

// ---------------------------------------------------------------------------
// Per-pixel attention: one wave per pixel. lane -> v = lane&31, khalf = lane>>5.
__global__ __launch_bounds__(256) void attn_k(const u16* __restrict__ qkv,
                                              u16* __restrict__ aout) {
  const int lane = threadIdx.x & 63;
  const int wv = threadIdx.x >> 6;
  const size_t p = (size_t)blockIdx.x * 4 + wv;
  const u16* row = qkv + p * NQKV;
  const int v = lane & 31;
  const int kh = lane >> 5;
#pragma unroll 1
  for (int h = 0; h < NHEADS; ++h) {
    const u16* base = row + h * QKVD;
    const float qv = bf2f(base[v]);
    const float vv = bf2f(base[1056 + v]);
    float part = 0.f;
#pragma unroll
    for (int i = 0; i < 16; ++i) {
      const int k = kh * 16 + i;
      const float qk = __shfl(qv, k);
      part = fmaf(qk, bf2f(base[32 + k * 32 + v]), part);
    }
    part += __shfl_xor(part, 32);
    const float s = part * 0.17677669529663687f;  // 1/sqrt(32)
    float mx = s;
#pragma unroll
    for (int off = 16; off; off >>= 1) mx = fmaxf(mx, __shfl_xor(mx, off));
    const float e = __expf(s - mx);
    float sum = e;
#pragma unroll
    for (int off = 16; off; off >>= 1) sum += __shfl_xor(sum, off);
    const float r = e / sum * vv;
    if (lane < 32) aout[p * 256 + h * 32 + v] = f2bf(r);
  }
}

// ---------------------------------------------------------------------------
extern "C" void kernel_launch(void* const* d_in, const int* in_sizes, int n_in,
                              void* d_out, int out_size, void* d_ws, size_t ws_size,
                              hipStream_t stream) {
  (void)in_sizes; (void)n_in; (void)out_size;
  const float* x = (const float*)d_in[0];     // (4, 256, 64, 64)
  const float* Wqkv = (const float*)d_in[1];  // (8, 1088, 256)
  const float* Wc = (const float*)d_in[2];    // (256, 256)
  const float* bc = (const float*)d_in[3];    // (256,)
  float* out = (float*)d_out;                 // (4, 256, 64, 64)
  char* ws = (char*)d_ws;

  // workspace layout (bytes)
  const size_t XBF_OFF = 0;                        // 16384*256*2  = 8388608
  const size_t WBF_OFF = 8388608;                  // 8704*256*2   = 4456448
  const size_t WCBF_OFF = 12845056;                // 256*256*2    = 131072
  const size_t ABF_OFF = 12976128;                 // 16384*256*2  = 8388608
  const size_t QKV_OFF = 21364736;                 // chunk*8704*2
  u16* Xbf = (u16*)(ws + XBF_OFF);
  u16* Wbf = (u16*)(ws + WBF_OFF);
  u16* Wcbf = (u16*)(ws + WCBF_OFF);
  u16* Abf = (u16*)(ws + ABF_OFF);
  u16* Qkv = (u16*)(ws + QKV_OFF);

  // pick largest pixel-chunk whose qkv slab fits the workspace
  size_t avail = (ws_size > QKV_OFF) ? (ws_size - QKV_OFF) : 0;
  int chunk = 8192;
  while (chunk > 256 && (size_t)chunk * NQKV * 2 > avail) chunk >>= 1;
  const int nchunks = NPIX_TOTAL / chunk;

  // stage 0: convert inputs to bf16
  transpose_cast<<<dim3(64, 4, 4), 256, 0, stream>>>(x, Xbf);
  cast_bf<<<(NQKV * CDIM) / 1024, 256, 0, stream>>>(Wqkv, Wbf, NQKV * CDIM);
  cast_bf<<<(CDIM * 256) / 1024, 256, 0, stream>>>(Wc, Wcbf, CDIM * 256);

  // stage 1+2: qkv GEMM (256^2 counted-vmcnt schedule) then per-pixel attention
  const int ntile_n = NQKV / 256;  // 34
  for (int c = 0; c < nchunks; ++c) {
    const size_t p0 = (size_t)c * chunk;
    gemm1_qkv<<<dim3((chunk / 256) * ntile_n), 512, 0, stream>>>(
        Xbf + p0 * CDIM, Wbf, Qkv, ntile_n);
    attn_k<<<chunk / 4, 256, 0, stream>>>(Qkv, Abf + p0 * 256);
  }

  // stage 3: out = a @ Wc^T + bc, written transposed to (B, C, 4096)
  gemm_out<<<dim3(256 / 128, NPIX_TOTAL / 128), 256, 0, stream>>>(
      Abf, Wcbf, out, bc);
}

// Round 4
// 113.393 us; speedup vs baseline: 2.0717x; 2.0717x over previous
//
#include <hip/hip_runtime.h>

// B=4, C=256, HS=WS=64 -> N=4096 pixels/batch, 16384 total.
// NK=NV=32, NH=8, QKV = 1088, NH*QKV = 8704.
#define NPIX_TOTAL 16384
#define CDIM 256
#define NHEADS 8
#define QKVD 1088
#define NQKV 8704

typedef unsigned short u16;
typedef __attribute__((ext_vector_type(8))) __bf16 bf16x8;
typedef __attribute__((ext_vector_type(4))) float f32x4;
typedef __attribute__((ext_vector_type(2))) unsigned u32x2;

__device__ static inline u16 f2bf(float f) {
  union { float f; unsigned u; } x; x.f = f;
  unsigned r = x.u + 0x7fffu + ((x.u >> 16) & 1u);
  return (u16)(r >> 16);
}

__device__ static inline void gload_lds16(const void* g, void* l) {
  __builtin_amdgcn_global_load_lds((const __attribute__((address_space(1))) void*)g,
                                   (__attribute__((address_space(3))) void*)l,
                                   16, 0, 0);
}

#define WAITVM(N) asm volatile("s_waitcnt vmcnt(" #N ")" ::: "memory")
#define BARRIER() asm volatile("s_barrier" ::: "memory")

// ---------------------------------------------------------------------------
__global__ __launch_bounds__(256) void transpose_cast(const float* __restrict__ x,
                                                      u16* __restrict__ xt) {
  __shared__ float t[64][65];
  const int b = blockIdx.z;
  const float* xb = x + (size_t)b * CDIM * 4096;
  u16* ob = xt + (size_t)b * 4096 * CDIM;
  const int n0 = blockIdx.x * 64;
  const int c0 = blockIdx.y * 64;
  const int tx = threadIdx.x & 63;
  const int ty = threadIdx.x >> 6;
#pragma unroll
  for (int i = 0; i < 16; ++i)
    t[ty + i * 4][tx] = xb[(size_t)(c0 + ty + i * 4) * 4096 + n0 + tx];
  __syncthreads();
#pragma unroll
  for (int i = 0; i < 16; ++i)
    ob[(size_t)(n0 + ty + i * 4) * CDIM + c0 + tx] = f2bf(t[tx][ty + i * 4]);
}

__global__ __launch_bounds__(256) void cast_bf(const float* __restrict__ in,
                                               u16* __restrict__ out, int n) {
  const int i = (blockIdx.x * 256 + threadIdx.x) * 4;
  if (i >= n) return;
  const f32x4 v = *(const f32x4*)(in + i);
  *(unsigned*)(out + i) = (unsigned)f2bf(v.x) | ((unsigned)f2bf(v.y) << 16);
  *(unsigned*)(out + i + 2) = (unsigned)f2bf(v.z) | ((unsigned)f2bf(v.w) << 16);
}

// ---------------------------------------------------------------------------
// Fused per-head qkv-GEMM + per-pixel attention.
// Block = 128 pixels x 1 head, 512 threads = 8 waves (2 M-halves x 4 N-quarters).
// X-tile (128x256 bf16, 64KB) LDS-resident; W streams: qv tile (64x256, 32KB)
// then 4 N-subtiles x 4 BK-slabs (256x64, 32KB each) double-buffered with
// counted vmcnt. Swapped-operand MFMA: lane&15=pixel, (lane>>4)*4+j=col.
// Per sub-GEMM s, frag(ni): k = s*8+wn*2+(ni>>1) (uniform), v=(ni&1)*16+hi*4+j
// (lane-local) -> qk accumulation is lane-local FMA with scalar q from LDS.
__global__ __launch_bounds__(512, 2) void fused_qkv_attn(const u16* __restrict__ Xbf,
                                                         const u16* __restrict__ Wbf,
                                                         u16* __restrict__ Abf) {
  __shared__ u16 A_lds[128 * 256];   // 64 KB, [row][32 chunks] swizzled
  __shared__ u16 B_lds[2 * 256 * 64];// 64 KB, dbuf slabs; prologue: qv tile; epilogue: partials
  __shared__ float q_lds[128 * 32];  // 16 KB, q[pix][k] swizzled chunks

  const int tid = threadIdx.x;
  const int lane = tid & 63;
  const int l15 = lane & 15;
  const int hi = lane >> 4;
  const int wid = tid >> 6;   // 0..7
  const int wr = wid >> 2;    // M half
  const int wn = wid & 3;     // N quarter
  const int wm = wr * 64;

  const int head = blockIdx.x & 7;           // head pinned per XCD
  const int pixtile = blockIdx.x >> 3;
  const u16* Ag = Xbf + (size_t)pixtile * 128 * CDIM;
  const u16* Wh = Wbf + (size_t)head * QKVD * CDIM;

  // ---- staging helpers (global source pre-swizzled, LDS linear) ----
  auto stageA = [&]() {
#pragma unroll
    for (int i = 0; i < 8; ++i) {
      const int seg = wid * 8 + i;
      const int L = seg * 64 + lane;         // 16B chunk 0..4095
      const int row = L >> 5;                // 0..127
      const int c = L & 31;
      const int cs = (c & 24) | ((c & 7) ^ (row & 7));
      gload_lds16(Ag + (size_t)row * CDIM + cs * 8, (char*)A_lds + (size_t)seg * 1024);
    }
  };
  auto stageQV = [&]() {
#pragma unroll
    for (int i = 0; i < 4; ++i) {
      const int seg = wid * 4 + i;
      const int L = seg * 64 + lane;         // 0..2047
      const int row = L >> 5;                // 0..63
      const int c = L & 31;
      const int cs = (c & 24) | ((c & 7) ^ (row & 7));
      const int grow = row < 32 ? row : row + 1024;  // q rows 0..31, v rows 1056..1087
      gload_lds16(Wh + (size_t)grow * CDIM + cs * 8, (char*)B_lds + (size_t)seg * 1024);
    }
  };
  auto stageB = [&](int buf, int t) {
#pragma unroll
    for (int i = 0; i < 4; ++i) {
      const int seg = wid * 4 + i;
      const int L = seg * 64 + lane;         // 0..2047
      const int row = L >> 3;                // 0..255
      const int c8 = (L & 7) ^ (row & 7);
      const int grow = 32 + (t >> 2) * 256 + row;
      gload_lds16(Wh + (size_t)grow * CDIM + (t & 3) * 64 + c8 * 8,
                  (char*)B_lds + (size_t)buf * 32768 + (size_t)seg * 1024);
    }
  };
  auto afrag = [&](int mi, int kb, int kk2) -> bf16x8 {
    const int row = wm + mi * 16 + l15;
    const int ch = kb * 8 + ((kk2 * 4 + hi) ^ (row & 7));
    return *(const bf16x8*)(A_lds + row * 256 + ch * 8);
  };

  // ---- prologue: X + qv tiles ----
  stageA();
  stageQV();
  WAITVM(0);
  __syncthreads();

  // qv sub-GEMM: each wave 64 pix x 16 cols (wn<2 -> q cols, wn>=2 -> v cols)
  f32x4 accq[4] = {};
#pragma unroll
  for (int kb = 0; kb < 4; ++kb)
#pragma unroll
    for (int kk2 = 0; kk2 < 2; ++kk2) {
      const int brow = wn * 16 + l15;
      const int bch = kb * 8 + ((kk2 * 4 + hi) ^ (brow & 7));
      const bf16x8 bq = *(const bf16x8*)(B_lds + brow * 256 + bch * 8);
#pragma unroll
      for (int mi = 0; mi < 4; ++mi)
        accq[mi] = __builtin_amdgcn_mfma_f32_16x16x32_bf16(bq, afrag(mi, kb, kk2),
                                                           accq[mi], 0, 0, 0);
    }
  if (wn < 2) {  // write q[pix][k] to LDS (k = wn*16+hi*4+j), chunk-swizzled
#pragma unroll
    for (int mi = 0; mi < 4; ++mi) {
      const int pix = wm + mi * 16 + l15;
      *(f32x4*)(q_lds + pix * 32 + ((wn * 4 + hi) ^ (pix & 7)) * 4) = accq[mi];
    }
  }
  __syncthreads();  // q visible; qv-tile reads done -> B_lds free for slabs

  // ---- main loop: 4 N-subtiles x 4 BK-steps, dbuf + counted vmcnt ----
  f32x4 acc[4][4] = {};
  f32x4 qkr[4][2] = {};
  stageB(0, 0);
  WAITVM(0);

#pragma unroll 1
  for (int s = 0; s < 4; ++s) {
#pragma unroll
    for (int kb = 0; kb < 4; ++kb) {
      const int t = s * 4 + kb;
      BARRIER();
      if (t < 15) stageB((t + 1) & 1, t + 1);
      const u16* bs = B_lds + (t & 1) * 16384;
#pragma unroll
      for (int kk2 = 0; kk2 < 2; ++kk2) {
        bf16x8 bfr[4], af[4];
#pragma unroll
        for (int ni = 0; ni < 4; ++ni) {
          const int row = wn * 64 + ni * 16 + l15;
          bfr[ni] = *(const bf16x8*)(bs + row * 64 + (((kk2 * 4 + hi) ^ (row & 7))) * 8);
        }
#pragma unroll
        for (int mi = 0; mi < 4; ++mi) af[mi] = afrag(mi, kb, kk2);
        __builtin_amdgcn_s_setprio(1);
#pragma unroll
        for (int mi = 0; mi < 4; ++mi)
#pragma unroll
          for (int ni = 0; ni < 4; ++ni)
            acc[mi][ni] = __builtin_amdgcn_mfma_f32_16x16x32_bf16(bfr[ni], af[mi],
                                                                  acc[mi][ni], 0, 0, 0);
        __builtin_amdgcn_s_setprio(0);
      }
      if (kb == 3) {
        // contraction: qk[pix][v] += q[pix][k] * K-val, lane-local
#pragma unroll
        for (int mi = 0; mi < 4; ++mi) {
          const int pix = wm + mi * 16 + l15;
          const float* qrow = q_lds + pix * 32;
#pragma unroll
          for (int kp = 0; kp < 2; ++kp) {
            const int k = s * 8 + wn * 2 + kp;
            const float qv_ = qrow[((k >> 2) ^ (pix & 7)) * 4 + (k & 3)];
            qkr[mi][0] += qv_ * acc[mi][kp * 2 + 0];
            qkr[mi][1] += qv_ * acc[mi][kp * 2 + 1];
          }
#pragma unroll
          for (int ni = 0; ni < 4; ++ni) acc[mi][ni] = (f32x4){0.f, 0.f, 0.f, 0.f};
        }
      }
      WAITVM(4);
    }
  }

  // ---- epilogue: cross-wave k-reduction + softmax + a = p*v ----
  __syncthreads();
  float* part = (float*)B_lds;  // [wn 4][pix 128][v 32] f32, chunk-swizzled
#pragma unroll
  for (int mi = 0; mi < 4; ++mi)
#pragma unroll
    for (int par = 0; par < 2; ++par) {
      const int pix = wm + mi * 16 + l15;
      const int ch = (par * 4 + hi) ^ (pix & 7);
      *(f32x4*)(part + wn * 4096 + pix * 32 + ch * 4) = qkr[mi][par];
    }
  __syncthreads();

  const float scale = 0.17677669529663687f;  // 1/sqrt(32)
#pragma unroll
  for (int mi = 0; mi < 4; ++mi) {
    const int pix = wm + mi * 16 + l15;
    const int ch0 = (0 * 4 + hi) ^ (pix & 7);
    const int ch1 = (1 * 4 + hi) ^ (pix & 7);
    f32x4 q0 = {0.f, 0.f, 0.f, 0.f}, q1 = {0.f, 0.f, 0.f, 0.f};
#pragma unroll
    for (int w = 0; w < 4; ++w) {
      q0 += *(const f32x4*)(part + w * 4096 + pix * 32 + ch0 * 4);
      q1 += *(const f32x4*)(part + w * 4096 + pix * 32 + ch1 * 4);
    }
    q0 *= scale; q1 *= scale;
    float m = fmaxf(fmaxf(fmaxf(q0.x, q0.y), fmaxf(q0.z, q0.w)),
                    fmaxf(fmaxf(q1.x, q1.y), fmaxf(q1.z, q1.w)));
    m = fmaxf(m, __shfl_xor(m, 16));
    m = fmaxf(m, __shfl_xor(m, 32));
    f32x4 e0, e1;
    e0.x = __expf(q0.x - m); e0.y = __expf(q0.y - m);
    e0.z = __expf(q0.z - m); e0.w = __expf(q0.w - m);
    e1.x = __expf(q1.x - m); e1.y = __expf(q1.y - m);
    e1.z = __expf(q1.z - m); e1.w = __expf(q1.w - m);
    float su = e0.x + e0.y + e0.z + e0.w + e1.x + e1.y + e1.z + e1.w;
    su += __shfl_xor(su, 16);
    su += __shfl_xor(su, 32);
    if (wn >= 2) {  // this wave holds v-values for par = wn-2; write a = p*v
      const float inv = 1.0f / su;
      const f32x4 a = (wn == 2 ? e0 : e1) * (accq[mi] * inv);
      u32x2 p;
      p.x = (unsigned)f2bf(a.x) | ((unsigned)f2bf(a.y) << 16);
      p.y = (unsigned)f2bf(a.z) | ((unsigned)f2bf(a.w) << 16);
      const size_t gp = (size_t)(pixtile * 128 + pix) * 256 + head * 32 + (wn - 2) * 16 + hi * 4;
      *(u32x2*)(Abf + gp) = p;
    }
  }
}

// ---------------------------------------------------------------------------
// gemm2: out = a @ Wc^T + bc, written transposed to (B, C, 4096). 128x128,
// 2-phase dbuf, swizzled (round-2 proven).
__global__ __launch_bounds__(256, 2) void gemm_out(const u16* __restrict__ A,
                                                   const u16* __restrict__ B,
                                                   float* __restrict__ Cout,
                                                   const float* __restrict__ bias) {
  __shared__ u16 As[2][128 * 64];
  __shared__ u16 Bs[2][128 * 64];
  const int tid = threadIdx.x;
  const int lane = tid & 63;
  const int wv = tid >> 6;
  const size_t m0 = (size_t)blockIdx.y * 128;
  const size_t n0 = (size_t)blockIdx.x * 128;
  const int wm = (wv >> 1) * 64;
  const int wn = (wv & 1) * 64;
  const int frow = lane & 15;
  const int fh = lane >> 4;
  const int fsw = frow & 7;

  f32x4 acc[4][4] = {};

  auto stage = [&](int buf, int kt) {
#pragma unroll
    for (int i = 0; i < 4; ++i) {
      const int L = (i * 4 + wv) * 64 + lane;
      const int r = L >> 3;
      const int cs = (L & 7) ^ (r & 7);
      const size_t goff = (size_t)r * CDIM + kt * 64 + cs * 8;
      gload_lds16(A + m0 * CDIM + goff, (char*)As[buf] + (size_t)(i * 4 + wv) * 1024);
      gload_lds16(B + n0 * CDIM + goff, (char*)Bs[buf] + (size_t)(i * 4 + wv) * 1024);
    }
  };

  stage(0, 0);
#pragma unroll
  for (int kt = 0; kt < 4; ++kt) {
    __syncthreads();
    if (kt < 3) stage((kt + 1) & 1, kt + 1);
    const u16* as = As[kt & 1];
    const u16* bs = Bs[kt & 1];
#pragma unroll
    for (int kk2 = 0; kk2 < 2; ++kk2) {
      const int kc = (kk2 * 4 + fh) ^ fsw;
      bf16x8 af[4], bfr[4];
#pragma unroll
      for (int mi = 0; mi < 4; ++mi)
        af[mi] = *(const bf16x8*)(as + (wm + mi * 16 + frow) * 64 + kc * 8);
#pragma unroll
      for (int ni = 0; ni < 4; ++ni)
        bfr[ni] = *(const bf16x8*)(bs + (wn + ni * 16 + frow) * 64 + kc * 8);
#pragma unroll
      for (int mi = 0; mi < 4; ++mi)
#pragma unroll
        for (int ni = 0; ni < 4; ++ni)
          acc[mi][ni] =
              __builtin_amdgcn_mfma_f32_16x16x32_bf16(af[mi], bfr[ni], acc[mi][ni], 0, 0, 0);
    }
  }

#pragma unroll
  for (int mi = 0; mi < 4; ++mi)
#pragma unroll
    for (int ni = 0; ni < 4; ++ni) {
      const size_t gm = m0 + wm + mi * 16 + fh * 4;
      const size_t gn = n0 + wn + ni * 16 + frow;
      f32x4 v = acc[mi][ni];
      v += bias[gn];
      const size_t b = gm >> 12;
      const size_t pix = gm & 4095;
      *(f32x4*)(Cout + ((b << 8) + gn) * 4096 + pix) = v;
    }
}

// ---------------------------------------------------------------------------
extern "C" void kernel_launch(void* const* d_in, const int* in_sizes, int n_in,
                              void* d_out, int out_size, void* d_ws, size_t ws_size,
                              hipStream_t stream) {
  (void)in_sizes; (void)n_in; (void)out_size; (void)ws_size;
  const float* x = (const float*)d_in[0];     // (4, 256, 64, 64)
  const float* Wqkv = (const float*)d_in[1];  // (8, 1088, 256)
  const float* Wc = (const float*)d_in[2];    // (256, 256)
  const float* bc = (const float*)d_in[3];    // (256,)
  float* out = (float*)d_out;                 // (4, 256, 64, 64)
  char* ws = (char*)d_ws;

  const size_t XBF_OFF = 0;               // 16384*256*2 = 8388608
  const size_t WBF_OFF = 8388608;         // 8704*256*2  = 4456448
  const size_t WCBF_OFF = 12845056;       // 256*256*2   = 131072
  const size_t ABF_OFF = 12976128;        // 16384*256*2 = 8388608
  u16* Xbf = (u16*)(ws + XBF_OFF);
  u16* Wbf = (u16*)(ws + WBF_OFF);
  u16* Wcbf = (u16*)(ws + WCBF_OFF);
  u16* Abf = (u16*)(ws + ABF_OFF);

  // stage 0: convert inputs to bf16
  transpose_cast<<<dim3(64, 4, 4), 256, 0, stream>>>(x, Xbf);
  cast_bf<<<(NQKV * CDIM) / 1024, 256, 0, stream>>>(Wqkv, Wbf, NQKV * CDIM);
  cast_bf<<<(CDIM * 256) / 1024, 256, 0, stream>>>(Wc, Wcbf, CDIM * 256);

  // stage 1: fused qkv-GEMM + attention (128 pixels x 1 head per block)
  fused_qkv_attn<<<dim3((NPIX_TOTAL / 128) * NHEADS), 512, 0, stream>>>(Xbf, Wbf, Abf);

  // stage 2: out = a @ Wc^T + bc -> (B, C, 4096)
  gemm_out<<<dim3(256 / 128, NPIX_TOTAL / 128), 256, 0, stream>>>(Abf, Wcbf, out, bc);
}